// Round 18
// baseline (125.898 us; speedup 1.0000x reference)
//
#include <hip/hip_runtime.h>
#include <hip/hip_bf16.h>
#include <stdint.h>

// ---------------------------------------------------------------------------
// GumbelQuantizer: z[32768,256] fp32, emb[1024,256] fp32 ->
//   out0 = softmax((-d + gumbel)) @ emb  (straight-through == quantized)
//   out1 = 1.25 * mean((quantized - z)^2)
// s_k = 2 z.e_k - |e_k|^2 (row-constant -|z|^2 cancels). Gumbel via exact JAX
// threefry2x32.
//
// R19: decouple the cipher from the fused kernel. The threefry burst (~560
// inst/tile-wave) ran at ~50% issue density inside the phase-locked main
// kernel. gq_gumbel precomputes g2 = -log2(-ln u) for all 33.5M elements
// (pure VALU, no barriers -> ~95% density, ~18us) into a 67MB ws array in
// EXACT fragment layout (bf16, pair-packed). Weight folded into exponent:
//   P propto exp2(2*log2e*aS + g2 - log2e*enk)
// -> main per-element cost: cvt+sub+fma+exp2 (v_exp_f32 IS 2^x). Main
// in-loop VALU drops ~75%. W is L3-resident (z32+W67+out32+E2=133MB<256).
// Fallback to the R14 cipher-in-loop path if ws_size < 69MB.
// Main kernel structure/layout otherwise byte-identical to R14 (90.9us).
// ---------------------------------------------------------------------------

typedef __bf16 bf16x8 __attribute__((ext_vector_type(8)));
typedef float  f32x4  __attribute__((ext_vector_type(4)));

#define MFMA16(A,B,C) __builtin_amdgcn_mfma_f32_16x16x32_bf16((A),(B),(C),0,0,0)

struct TF2 { uint32_t a, b; };

__host__ __device__ constexpr uint32_t rotl32(uint32_t v, int r){ return (v<<r)|(v>>(32-r)); }

// Threefry-2x32, 20 rounds — exact JAX implementation.
__host__ __device__ constexpr TF2 tf2x32(uint32_t k0, uint32_t k1, uint32_t x0, uint32_t x1){
  const uint32_t k2 = k0 ^ k1 ^ 0x1BD11BDAu;
  x0 += k0; x1 += k1;
  x0 += x1; x1 = rotl32(x1,13); x1 ^= x0;
  x0 += x1; x1 = rotl32(x1,15); x1 ^= x0;
  x0 += x1; x1 = rotl32(x1,26); x1 ^= x0;
  x0 += x1; x1 = rotl32(x1, 6); x1 ^= x0;
  x0 += k1; x1 += k2 + 1u;
  x0 += x1; x1 = rotl32(x1,17); x1 ^= x0;
  x0 += x1; x1 = rotl32(x1,29); x1 ^= x0;
  x0 += x1; x1 = rotl32(x1,16); x1 ^= x0;
  x0 += x1; x1 = rotl32(x1,24); x1 ^= x0;
  x0 += k2; x1 += k0 + 2u;
  x0 += x1; x1 = rotl32(x1,13); x1 ^= x0;
  x0 += x1; x1 = rotl32(x1,15); x1 ^= x0;
  x0 += x1; x1 = rotl32(x1,26); x1 ^= x0;
  x0 += x1; x1 = rotl32(x1, 6); x1 ^= x0;
  x0 += k0; x1 += k1 + 3u;
  x0 += x1; x1 = rotl32(x1,17); x1 ^= x0;
  x0 += x1; x1 = rotl32(x1,29); x1 ^= x0;
  x0 += x1; x1 = rotl32(x1,16); x1 ^= x0;
  x0 += x1; x1 = rotl32(x1,24); x1 ^= x0;
  x0 += k1; x1 += k2 + 4u;
  x0 += x1; x1 = rotl32(x1,13); x1 ^= x0;
  x0 += x1; x1 = rotl32(x1,15); x1 ^= x0;
  x0 += x1; x1 = rotl32(x1,26); x1 ^= x0;
  x0 += x1; x1 = rotl32(x1, 6); x1 ^= x0;
  x0 += k2; x1 += k0 + 5u;
  return {x0, x1};
}

// gkey = fold_in(key(0), 1) = threefry((0,0), (0,1)) — compile-time.
constexpr TF2 GKEY = tf2x32(0u, 0u, 0u, 1u);

__device__ __forceinline__ unsigned short f2bf(float f){
  __bf16 h = (__bf16)f;
  return __builtin_bit_cast(unsigned short, h);
}

// exp(gumbel) up to a global constant: 1/(-log2 u), u = JAX uniform(tiny,1)
__device__ __forceinline__ float gumbel_w(uint32_t bits){
  float uf = __uint_as_float((bits >> 9) | 0x3f800000u) - 1.0f;
  float u  = fmaxf(uf, 1.17549435e-38f);
  return __builtin_amdgcn_rcpf(-__log2f(u));
}

// g2 = -log2(-ln u): gumbel exponent in log2 units (2^g2 = e^g / ln2-factor,
// the global factor cancels in softmax).
__device__ __forceinline__ float g2f(uint32_t bits){
  float uf = __uint_as_float((bits >> 9) | 0x3f800000u) - 1.0f;
  float u  = fmaxf(uf, 1.17549435e-38f);
  float t  = __log2f(u) * (-0.69314718056f);   // = -ln u  (> 0)
  return -__log2f(t);
}

// ---------------------------------------------------------------------------
// Prep: bf16 E [1024][256], bf16 E^T [256][1024], |e_k|^2 fp32 [1024]
// ---------------------------------------------------------------------------
__global__ void gq_prep(const float* __restrict__ emb, unsigned short* __restrict__ Eb,
                        unsigned short* __restrict__ ETb, float* __restrict__ enorm)
{
  const int r = blockIdx.x;       // 1024 emb rows
  const int t = threadIdx.x;      // 256 threads = one row
  float e = emb[r*256 + t];
  unsigned short h = f2bf(e);
  Eb[r*256 + t] = h;
  ETb[t*1024 + r] = h;
  float sq = e*e;
  #pragma unroll
  for (int o = 32; o > 0; o >>= 1) sq += __shfl_down(sq, o);
  __shared__ float ws4[4];
  if ((t & 63) == 0) ws4[t >> 6] = sq;
  __syncthreads();
  if (t == 0) enorm[r] = ws4[0] + ws4[1] + ws4[2] + ws4[3];
}

// ---------------------------------------------------------------------------
// Gumbel precompute: thread <-> (b, kt, wv, lane); 8 cipher pairs each.
// W layout (bf16, pair-packed u32): thread gt writes 32B at W + gt*32:
//   u32[rt*4+rg] = pack(g2(G0 row rowL), g2(G1 row rowL+32^))
// matching gq_main_w's (rt, rg) fragment enumeration exactly.
// ---------------------------------------------------------------------------
__global__ __launch_bounds__(256) void gq_gumbel(uint32_t* __restrict__ W)
{
  int gt   = blockIdx.x * 256 + threadIdx.x;  // 0 .. 2,097,151
  int lane = gt & 63;
  int wvv  = (gt >> 6) & 7;
  int kt   = (gt >> 9) & 7;
  int b    = gt >> 12;                        // 0..511
  int col  = lane & 15;
  int hi   = lane >> 4;
  int ke   = kt*128 + wvv*16 + col;
  uint32_t* wp = W + (size_t)gt * 8;
  #pragma unroll
  for (int rt = 0; rt < 2; ++rt) {
    #pragma unroll
    for (int rg = 0; rg < 4; ++rg) {
      int rowL = rt*16 + hi*4 + rg;
      uint32_t idx = (uint32_t)(b*32 + rowL)*1024u + (uint32_t)ke;
      TF2 cc = tf2x32(GKEY.a, GKEY.b, idx, idx + (1u<<24));   // (t, t+16384)
      wp[rt*4 + rg] = (uint32_t)f2bf(g2f(cc.a))
                    | ((uint32_t)f2bf(g2f(cc.b)) << 16);
    }
  }
}

// ---------------------------------------------------------------------------
// Main (W-fed): 512 blocks x 512 threads (8 waves), 2 blocks/CU, 64K LDS.
// Identical to R14 except: ciphers replaced by 2x bf16x8 W loads; P computed
// as exp2(fmaf(2*log2e, aS, g2 - enk*log2e)).
// LDS (unit-major, 16B units, zero-VALU addressing):
//   zb3 [0,32768):      unit(kk,hi,row), byte = kk*4096 + hi*1024 + row*16
//   Pl2 [32768,65536):  2 x 16K buffers, unit(kk4,hi,row)
// ---------------------------------------------------------------------------
__global__ __launch_bounds__(512, 2)
void gq_main_w(
    const float* __restrict__ z, const unsigned short* __restrict__ Eb,
    const unsigned short* __restrict__ ETb, const float* __restrict__ enorm,
    const unsigned short* __restrict__ W,
    float* __restrict__ out, float* __restrict__ partials)
{
  __shared__ __align__(16) unsigned char sm[32768 + 32768];
  float* denomW = (float*)(sm + 32768);                // reuse Pl2: [8][64]
  float* denomF = (float*)(sm + 32768 + 2048);         // [64]
  float* lsumW  = (float*)(sm + 32768 + 2048 + 256);   // [8]

  const int tid  = threadIdx.x;
  const int lane = tid & 63;
  const int wv   = tid >> 6;        // wave 0..7
  const int col  = lane & 15;
  const int hi   = lane >> 4;       // 0..3
  const int b32  = blockIdx.x * 32;

  // ---- stage z: fp32 -> bf16 unit-major zb3 ----
  #pragma unroll
  for (int j = 0; j < 4; ++j) {
    int lin = j*512 + tid;              // 0..2047 units
    int row = lin >> 5;                 // 0..63
    int u   = lin & 31;                 // 0..31
    int grow = (row < 32) ? (b32 + row) : (16384 + b32 + row - 32);
    const float4* src = reinterpret_cast<const float4*>(z + (size_t)grow*256 + u*8);
    float4 v0 = src[0], v1 = src[1];
    uint32_t w0 = (uint32_t)f2bf(v0.x) | ((uint32_t)f2bf(v0.y) << 16);
    uint32_t w1 = (uint32_t)f2bf(v0.z) | ((uint32_t)f2bf(v0.w) << 16);
    uint32_t w2 = (uint32_t)f2bf(v1.x) | ((uint32_t)f2bf(v1.y) << 16);
    uint32_t w3 = (uint32_t)f2bf(v1.z) | ((uint32_t)f2bf(v1.w) << 16);
    uint32_t* p = reinterpret_cast<uint32_t*>(sm + u*1024 + row*16);
    p[0] = w0; p[1] = w1; p[2] = w2; p[3] = w3;
  }
  __syncthreads();

  f32x4 accQ[4][2] = {};      // Q accumulator: 4 row-tiles x 2 d-col-tiles
  float dn[4][4] = {};        // denominator partials per (row-tile, reg)
  float lsum = 0.0f;

  const unsigned char* zA = sm + (hi*1024 + col*16);            // m1 A reads
  const int pstore_off = (wv >> 1)*4096 + ((((wv & 1) << 1) | (col >> 3)))*1024
                       + hi*64 + (col & 7)*2;
  // W base for this (block, wave, lane): ushort index
  const unsigned short* wlane = W + (((size_t)blockIdx.x*8)*8 + wv)*1024 + lane*16;

  #pragma unroll 1
  for (int kt = 0; kt < 8; ++kt) {
    const int ke0 = kt*128 + wv*16;     // this wave's emb-row base
    const int pbuf = 32768 + (kt & 1)*16384;

    // ---- region 1: mb + W prefetch + m1 MFMAs ----
    const unsigned short* ebase = Eb + (size_t)(ke0 + col)*256 + hi*8;
    bf16x8 mb[8];
    #pragma unroll
    for (int kk = 0; kk < 8; ++kk)
      mb[kk] = *reinterpret_cast<const bf16x8*>(ebase + kk*32);

    const unsigned short* wtile = wlane + (size_t)kt*8*1024;
    bf16x8 wb0 = *reinterpret_cast<const bf16x8*>(wtile);       // rt=0: rg x {a,b}
    bf16x8 wb1 = *reinterpret_cast<const bf16x8*>(wtile + 8);   // rt=1

    float enkS = enorm[ke0 + col] * 1.44269504f;   // log2e units

    f32x4 aS[4] = {};
    __builtin_amdgcn_s_setprio(1);
    #pragma unroll
    for (int kk = 0; kk < 8; ++kk) {
      #pragma unroll
      for (int rt = 0; rt < 4; ++rt) {
        bf16x8 af = *reinterpret_cast<const bf16x8*>(zA + kk*4096 + rt*256);
        aS[rt] = MFMA16(af, mb[kk], aS[rt]);
      }
    }
    __builtin_amdgcn_s_setprio(0);

    // ---- region 2: nb prefetch + exp2/pack/store P ----
    const unsigned short* etb0 = ETb + (size_t)(wv*32 + col)*1024 + kt*128 + hi*8;
    const unsigned short* etb1 = etb0 + 16*1024;
    bf16x8 nb[8];
    #pragma unroll
    for (int kk = 0; kk < 4; ++kk) {
      nb[kk]   = *reinterpret_cast<const bf16x8*>(etb0 + kk*32);
      nb[kk+4] = *reinterpret_cast<const bf16x8*>(etb1 + kk*32);
    }

    unsigned char* sb = sm + pbuf + pstore_off;
    #pragma unroll
    for (int rt = 0; rt < 2; ++rt) {
      #pragma unroll
      for (int rg = 0; rg < 4; ++rg) {
        float g2a = (float)((rt == 0) ? wb0[2*rg]   : wb1[2*rg]);
        float g2b = (float)((rt == 0) ? wb0[2*rg+1] : wb1[2*rg+1]);
        // P = 2^(2*log2e*aS + g2 - enkS); global factors cancel in softmax
        float p0 = exp2f(fmaf(2.88539008f, aS[rt  ][rg], g2a - enkS));
        float p1 = exp2f(fmaf(2.88539008f, aS[rt+2][rg], g2b - enkS));
        dn[rt  ][rg] += p0;
        dn[rt+2][rg] += p1;
        *(unsigned short*)(sb + rt*256 + rg*16)       = f2bf(p0);  // rows 0..31
        *(unsigned short*)(sb + rt*256 + rg*16 + 512) = f2bf(p1);  // rows 32..63
      }
    }
    __syncthreads();

    // ---- region 3: m2 MFMAs (P via base+imm) ----
    const unsigned char* pA = sm + pbuf + (hi*1024 + col*16);
    __builtin_amdgcn_s_setprio(1);
    #pragma unroll
    for (int kk = 0; kk < 4; ++kk) {
      #pragma unroll
      for (int rt = 0; rt < 4; ++rt) {
        bf16x8 af = *reinterpret_cast<const bf16x8*>(pA + kk*4096 + rt*256);
        accQ[rt][0] = MFMA16(af, nb[kk],   accQ[rt][0]);
        accQ[rt][1] = MFMA16(af, nb[kk+4], accQ[rt][1]);
      }
    }
    __builtin_amdgcn_s_setprio(0);
    // no second barrier: next iteration writes the other P buffer
  }
  __syncthreads();   // protect reduction-scratch reuse of Pl2

  // ---- denominator reduce ----
  #pragma unroll
  for (int rt = 0; rt < 4; ++rt)
    #pragma unroll
    for (int rg = 0; rg < 4; ++rg) {
      float v = dn[rt][rg];
      v += __shfl_xor(v, 1);
      v += __shfl_xor(v, 2);
      v += __shfl_xor(v, 4);
      v += __shfl_xor(v, 8);
      dn[rt][rg] = v;
    }
  if (col == 0) {
    #pragma unroll
    for (int rt = 0; rt < 4; ++rt)
      #pragma unroll
      for (int rg = 0; rg < 4; ++rg)
        denomW[wv*64 + rt*16 + hi*4 + rg] = dn[rt][rg];
  }
  __syncthreads();
  if (tid < 64) {
    float s = 0.f;
    #pragma unroll
    for (int w2 = 0; w2 < 8; ++w2) s += denomW[w2*64 + tid];
    denomF[tid] = __builtin_amdgcn_rcpf(s);
  }
  __syncthreads();

  // ---- epilogue: normalize, write out0, loss partial ----
  #pragma unroll
  for (int rt = 0; rt < 4; ++rt) {
    #pragma unroll
    for (int rg = 0; rg < 4; ++rg) {
      int row = rt*16 + hi*4 + rg;
      float rd = denomF[row];
      int grow = (row < 32) ? (b32 + row) : (16384 + b32 + row - 32);
      float* orow = out + (size_t)grow*256;
      const float* zrow = z + (size_t)grow*256;
      #pragma unroll
      for (int ct = 0; ct < 2; ++ct) {
        int d = wv*32 + ct*16 + col;
        float q  = accQ[rt][ct][rg] * rd;
        float zv = zrow[d];
        float df = q - zv;
        orow[d] = zv + df;          // straight-through value == quantized
        lsum += df*df;
      }
    }
  }
  #pragma unroll
  for (int o = 32; o > 0; o >>= 1) lsum += __shfl_down(lsum, o);
  if (lane == 0) lsumW[wv] = lsum;
  __syncthreads();
  if (tid == 0) {
    float s = 0.f;
    #pragma unroll
    for (int w2 = 0; w2 < 8; ++w2) s += lsumW[w2];
    partials[blockIdx.x] = s;
  }
}

// ---------------------------------------------------------------------------
// Fallback main (R14, cipher-in-loop) — used when ws_size is too small for W.
// ---------------------------------------------------------------------------
__global__ __launch_bounds__(512, 2)
void gq_main_fb(
    const float* __restrict__ z, const unsigned short* __restrict__ Eb,
    const unsigned short* __restrict__ ETb, const float* __restrict__ enorm,
    float* __restrict__ out, float* __restrict__ partials)
{
  __shared__ __align__(16) unsigned char sm[32768 + 32768];
  float* denomW = (float*)(sm + 32768);
  float* denomF = (float*)(sm + 32768 + 2048);
  float* lsumW  = (float*)(sm + 32768 + 2048 + 256);

  const int tid  = threadIdx.x;
  const int lane = tid & 63;
  const int wv   = tid >> 6;
  const int col  = lane & 15;
  const int hi   = lane >> 4;
  const int b32  = blockIdx.x * 32;

  #pragma unroll
  for (int j = 0; j < 4; ++j) {
    int lin = j*512 + tid;
    int row = lin >> 5;
    int u   = lin & 31;
    int grow = (row < 32) ? (b32 + row) : (16384 + b32 + row - 32);
    const float4* src = reinterpret_cast<const float4*>(z + (size_t)grow*256 + u*8);
    float4 v0 = src[0], v1 = src[1];
    uint32_t w0 = (uint32_t)f2bf(v0.x) | ((uint32_t)f2bf(v0.y) << 16);
    uint32_t w1 = (uint32_t)f2bf(v0.z) | ((uint32_t)f2bf(v0.w) << 16);
    uint32_t w2 = (uint32_t)f2bf(v1.x) | ((uint32_t)f2bf(v1.y) << 16);
    uint32_t w3 = (uint32_t)f2bf(v1.z) | ((uint32_t)f2bf(v1.w) << 16);
    uint32_t* p = reinterpret_cast<uint32_t*>(sm + u*1024 + row*16);
    p[0] = w0; p[1] = w1; p[2] = w2; p[3] = w3;
  }
  __syncthreads();

  f32x4 accQ[4][2] = {};
  float dn[4][4] = {};
  float lsum = 0.0f;

  const unsigned char* zA = sm + (hi*1024 + col*16);
  const int pstore_off = (wv >> 1)*4096 + ((((wv & 1) << 1) | (col >> 3)))*1024
                       + hi*64 + (col & 7)*2;

  #pragma unroll 1
  for (int kt = 0; kt < 8; ++kt) {
    const int ke0 = kt*128 + wv*16;
    const int pbuf = 32768 + (kt & 1)*16384;

    const unsigned short* ebase = Eb + (size_t)(ke0 + col)*256 + hi*8;
    bf16x8 mb[8];
    #pragma unroll
    for (int kk = 0; kk < 8; ++kk)
      mb[kk] = *reinterpret_cast<const bf16x8*>(ebase + kk*32);

    float enk = enorm[ke0 + col];

    TF2 c[2][4];
    #pragma unroll
    for (int rt = 0; rt < 2; ++rt) {
      #pragma unroll
      for (int rg = 0; rg < 4; ++rg) {
        int rowL = rt*16 + hi*4 + rg;
        uint32_t idx = (uint32_t)(b32 + rowL)*1024u + (uint32_t)(ke0 + col);
        c[rt][rg] = tf2x32(GKEY.a, GKEY.b, idx, idx + (1u<<24));
      }
    }

    f32x4 aS[4] = {};
    __builtin_amdgcn_s_setprio(1);
    #pragma unroll
    for (int kk = 0; kk < 8; ++kk) {
      #pragma unroll
      for (int rt = 0; rt < 4; ++rt) {
        bf16x8 af = *reinterpret_cast<const bf16x8*>(zA + kk*4096 + rt*256);
        aS[rt] = MFMA16(af, mb[kk], aS[rt]);
      }
    }
    __builtin_amdgcn_s_setprio(0);

    const unsigned short* etb0 = ETb + (size_t)(wv*32 + col)*1024 + kt*128 + hi*8;
    const unsigned short* etb1 = etb0 + 16*1024;
    bf16x8 nb[8];
    #pragma unroll
    for (int kk = 0; kk < 4; ++kk) {
      nb[kk]   = *reinterpret_cast<const bf16x8*>(etb0 + kk*32);
      nb[kk+4] = *reinterpret_cast<const bf16x8*>(etb1 + kk*32);
    }

    unsigned char* sb = sm + pbuf + pstore_off;
    #pragma unroll
    for (int rt = 0; rt < 2; ++rt) {
      #pragma unroll
      for (int rg = 0; rg < 4; ++rg) {
        float p0 = __expf(fmaf(2.0f, aS[rt  ][rg], -enk)) * gumbel_w(c[rt][rg].a);
        float p1 = __expf(fmaf(2.0f, aS[rt+2][rg], -enk)) * gumbel_w(c[rt][rg].b);
        dn[rt  ][rg] += p0;
        dn[rt+2][rg] += p1;
        *(unsigned short*)(sb + rt*256 + rg*16)       = f2bf(p0);
        *(unsigned short*)(sb + rt*256 + rg*16 + 512) = f2bf(p1);
      }
    }
    __syncthreads();

    const unsigned char* pA = sm + pbuf + (hi*1024 + col*16);
    __builtin_amdgcn_s_setprio(1);
    #pragma unroll
    for (int kk = 0; kk < 4; ++kk) {
      #pragma unroll
      for (int rt = 0; rt < 4; ++rt) {
        bf16x8 af = *reinterpret_cast<const bf16x8*>(pA + kk*4096 + rt*256);
        accQ[rt][0] = MFMA16(af, nb[kk],   accQ[rt][0]);
        accQ[rt][1] = MFMA16(af, nb[kk+4], accQ[rt][1]);
      }
    }
    __builtin_amdgcn_s_setprio(0);
  }
  __syncthreads();

  #pragma unroll
  for (int rt = 0; rt < 4; ++rt)
    #pragma unroll
    for (int rg = 0; rg < 4; ++rg) {
      float v = dn[rt][rg];
      v += __shfl_xor(v, 1);
      v += __shfl_xor(v, 2);
      v += __shfl_xor(v, 4);
      v += __shfl_xor(v, 8);
      dn[rt][rg] = v;
    }
  if (col == 0) {
    #pragma unroll
    for (int rt = 0; rt < 4; ++rt)
      #pragma unroll
      for (int rg = 0; rg < 4; ++rg)
        denomW[wv*64 + rt*16 + hi*4 + rg] = dn[rt][rg];
  }
  __syncthreads();
  if (tid < 64) {
    float s = 0.f;
    #pragma unroll
    for (int w2 = 0; w2 < 8; ++w2) s += denomW[w2*64 + tid];
    denomF[tid] = __builtin_amdgcn_rcpf(s);
  }
  __syncthreads();

  #pragma unroll
  for (int rt = 0; rt < 4; ++rt) {
    #pragma unroll
    for (int rg = 0; rg < 4; ++rg) {
      int row = rt*16 + hi*4 + rg;
      float rd = denomF[row];
      int grow = (row < 32) ? (b32 + row) : (16384 + b32 + row - 32);
      float* orow = out + (size_t)grow*256;
      const float* zrow = z + (size_t)grow*256;
      #pragma unroll
      for (int ct = 0; ct < 2; ++ct) {
        int d = wv*32 + ct*16 + col;
        float q  = accQ[rt][ct][rg] * rd;
        float zv = zrow[d];
        float df = q - zv;
        orow[d] = zv + df;
        lsum += df*df;
      }
    }
  }
  #pragma unroll
  for (int o = 32; o > 0; o >>= 1) lsum += __shfl_down(lsum, o);
  if (lane == 0) lsumW[wv] = lsum;
  __syncthreads();
  if (tid == 0) {
    float s = 0.f;
    #pragma unroll
    for (int w2 = 0; w2 < 8; ++w2) s += lsumW[w2];
    partials[blockIdx.x] = s;
  }
}

// ---------------------------------------------------------------------------
// Final: loss = 1.25 * sum(partials) / 2^23
// ---------------------------------------------------------------------------
__global__ void gq_final(const float* __restrict__ partials, float* __restrict__ out)
{
  const int t = threadIdx.x;   // 512
  float v = partials[t];
  #pragma unroll
  for (int o = 32; o > 0; o >>= 1) v += __shfl_down(v, o);
  __shared__ float ws8[8];
  if ((t & 63) == 0) ws8[t >> 6] = v;
  __syncthreads();
  if (t == 0) {
    float s = 0.f;
    #pragma unroll
    for (int i = 0; i < 8; ++i) s += ws8[i];
    out[8388608] = 1.25f * s * (1.0f / 8388608.0f);
  }
}

extern "C" void kernel_launch(void* const* d_in, const int* in_sizes, int n_in,
                              void* d_out, int out_size, void* d_ws, size_t ws_size,
                              hipStream_t stream)
{
  const float* z   = (const float*)d_in[0];   // [32,1024,256]
  const float* emb = (const float*)d_in[1];   // [1024,256]
  float* out = (float*)d_out;                 // 8388608 + 1
  char* ws = (char*)d_ws;
  unsigned short* Eb  = (unsigned short*)ws;               // 524288 B
  unsigned short* ETb = (unsigned short*)(ws + 524288);    // 524288 B
  float* enorm    = (float*)(ws + 1048576);                // 4096 B
  float* partials = (float*)(ws + 1048576 + 4096);         // 4096 B
  const size_t W_OFF  = 1056768;                           // 1MB + 8KB
  const size_t W_SIZE = 67108864;                          // 512*8*8*64*32 B

  gq_prep<<<1024, 256, 0, stream>>>(emb, Eb, ETb, enorm);
  if (ws_size >= W_OFF + W_SIZE) {
    uint32_t* W = (uint32_t*)(ws + W_OFF);
    gq_gumbel<<<8192, 256, 0, stream>>>(W);
    gq_main_w<<<512, 512, 0, stream>>>(z, Eb, ETb, enorm,
                                       (const unsigned short*)W, out, partials);
  } else {
    gq_main_fb<<<512, 512, 0, stream>>>(z, Eb, ETb, enorm, out, partials);
  }
  gq_final<<<1, 512, 0, stream>>>(partials, out);
}

// Round 19
// 92.505 us; speedup vs baseline: 1.3610x; 1.3610x over previous
//
#include <hip/hip_runtime.h>
#include <hip/hip_bf16.h>
#include <stdint.h>

// ---------------------------------------------------------------------------
// GumbelQuantizer: z[32768,256] fp32, emb[1024,256] fp32 ->
//   out0 = softmax((-d + gumbel)) @ emb  (straight-through == quantized)
//   out1 = 1.25 * mean((quantized - z)^2)
// s_k = 2 z.e_k - |e_k|^2 (row-constant -|z|^2 cancels). Gumbel via exact JAX
// threefry2x32; e^g = rcp(-log2 u) (global 1/ln2 cancels in softmax).
//
// R20 = R14 (90.9us best) + rt=0 A-fragments register-resident.
// R19's split proved the kernel is NOT VALU-bound (VALUBusy 18.5% at same
// speed): the cost is LDS traffic + latency chains + barrier phase-lock.
// m1 re-reads the same 32KB z-tile from LDS every k-tile (48 b128/tile-wave).
// Rows 0-15 (rt=0) now live in 32 VGPRs for the whole kernel (azc, loaded
// once from global/L3): m1 LDS reads 48->40 per tile-wave (-17%), staging
// skips rows 0-15 (-25%). VGPR 72->~104, under the (512,2)=128 budget at
// unchanged 2-blocks/CU occupancy. Everything else byte-identical to R14.
// ---------------------------------------------------------------------------

typedef __bf16 bf16x8 __attribute__((ext_vector_type(8)));
typedef float  f32x4  __attribute__((ext_vector_type(4)));

#define MFMA16(A,B,C) __builtin_amdgcn_mfma_f32_16x16x32_bf16((A),(B),(C),0,0,0)

struct TF2 { uint32_t a, b; };

__host__ __device__ constexpr uint32_t rotl32(uint32_t v, int r){ return (v<<r)|(v>>(32-r)); }

// Threefry-2x32, 20 rounds — exact JAX implementation.
__host__ __device__ constexpr TF2 tf2x32(uint32_t k0, uint32_t k1, uint32_t x0, uint32_t x1){
  const uint32_t k2 = k0 ^ k1 ^ 0x1BD11BDAu;
  x0 += k0; x1 += k1;
  x0 += x1; x1 = rotl32(x1,13); x1 ^= x0;
  x0 += x1; x1 = rotl32(x1,15); x1 ^= x0;
  x0 += x1; x1 = rotl32(x1,26); x1 ^= x0;
  x0 += x1; x1 = rotl32(x1, 6); x1 ^= x0;
  x0 += k1; x1 += k2 + 1u;
  x0 += x1; x1 = rotl32(x1,17); x1 ^= x0;
  x0 += x1; x1 = rotl32(x1,29); x1 ^= x0;
  x0 += x1; x1 = rotl32(x1,16); x1 ^= x0;
  x0 += x1; x1 = rotl32(x1,24); x1 ^= x0;
  x0 += k2; x1 += k0 + 2u;
  x0 += x1; x1 = rotl32(x1,13); x1 ^= x0;
  x0 += x1; x1 = rotl32(x1,15); x1 ^= x0;
  x0 += x1; x1 = rotl32(x1,26); x1 ^= x0;
  x0 += x1; x1 = rotl32(x1, 6); x1 ^= x0;
  x0 += k0; x1 += k1 + 3u;
  x0 += x1; x1 = rotl32(x1,17); x1 ^= x0;
  x0 += x1; x1 = rotl32(x1,29); x1 ^= x0;
  x0 += x1; x1 = rotl32(x1,16); x1 ^= x0;
  x0 += x1; x1 = rotl32(x1,24); x1 ^= x0;
  x0 += k1; x1 += k2 + 4u;
  x0 += x1; x1 = rotl32(x1,13); x1 ^= x0;
  x0 += x1; x1 = rotl32(x1,15); x1 ^= x0;
  x0 += x1; x1 = rotl32(x1,26); x1 ^= x0;
  x0 += x1; x1 = rotl32(x1, 6); x1 ^= x0;
  x0 += k2; x1 += k0 + 5u;
  return {x0, x1};
}

// gkey = fold_in(key(0), 1) = threefry((0,0), (0,1)) — compile-time.
constexpr TF2 GKEY = tf2x32(0u, 0u, 0u, 1u);

__device__ __forceinline__ unsigned short f2bf(float f){
  __bf16 h = (__bf16)f;
  return __builtin_bit_cast(unsigned short, h);
}

// exp(gumbel) up to a global constant: 1/(-log2 u), u = JAX uniform(tiny,1)
__device__ __forceinline__ float gumbel_w(uint32_t bits){
  float uf = __uint_as_float((bits >> 9) | 0x3f800000u) - 1.0f;
  float u  = fmaxf(uf, 1.17549435e-38f);
  return __builtin_amdgcn_rcpf(-__log2f(u));
}

__device__ __forceinline__ bf16x8 pack8(float4 a, float4 b){
  bf16x8 r;
  r[0]=(__bf16)a.x; r[1]=(__bf16)a.y; r[2]=(__bf16)a.z; r[3]=(__bf16)a.w;
  r[4]=(__bf16)b.x; r[5]=(__bf16)b.y; r[6]=(__bf16)b.z; r[7]=(__bf16)b.w;
  return r;
}

// ---------------------------------------------------------------------------
// Prep: bf16 E [1024][256], bf16 E^T [256][1024], |e_k|^2 fp32 [1024]
// ---------------------------------------------------------------------------
__global__ void gq_prep(const float* __restrict__ emb, unsigned short* __restrict__ Eb,
                        unsigned short* __restrict__ ETb, float* __restrict__ enorm)
{
  const int r = blockIdx.x;       // 1024 emb rows
  const int t = threadIdx.x;      // 256 threads = one row
  float e = emb[r*256 + t];
  unsigned short h = f2bf(e);
  Eb[r*256 + t] = h;
  ETb[t*1024 + r] = h;
  float sq = e*e;
  #pragma unroll
  for (int o = 32; o > 0; o >>= 1) sq += __shfl_down(sq, o);
  __shared__ float ws4[4];
  if ((t & 63) == 0) ws4[t >> 6] = sq;
  __syncthreads();
  if (t == 0) enorm[r] = ws4[0] + ws4[1] + ws4[2] + ws4[3];
}

// ---------------------------------------------------------------------------
// Main fused kernel: 512 blocks x 512 threads (8 waves), 2 blocks/CU.
// Block b owns z rows [b*32, b*32+32) (G0) and +16384 (G1) — threefry pairs.
// LDS layout (unit-major, 16B units, zero-VALU addressing):
//   zb3  at [0, 32768):       unit(kk 0..7, hi 0..3, row 0..63) =
//                             z[row][kk*32+hi*8 .. +7] bf16
//                             byte = kk*4096 + hi*1024 + row*16
//                             rows 0..15 NOT staged (live in azc registers)
//   Pl2  at [32768, 65536):   2 buffers x 16KB; unit(kk 0..3, hi, row)
// All ds accesses: one lane-resident base reg + compile-time offset.
// Wave w owns emb-col stripe w*16 per 128-k tile (m1/gumbel) and d-cols
// [w*32,+32) of the output (m2).
// ---------------------------------------------------------------------------
__global__ __launch_bounds__(512, 2)   // empirically: 128-VGPR budget
void gq_main(
    const float* __restrict__ z, const unsigned short* __restrict__ Eb,
    const unsigned short* __restrict__ ETb, const float* __restrict__ enorm,
    float* __restrict__ out, float* __restrict__ partials)
{
  __shared__ __align__(16) unsigned char sm[32768 + 32768];
  float* denomW = (float*)(sm + 32768);                // reuse Pl2: [8][64]
  float* denomF = (float*)(sm + 32768 + 2048);         // [64]
  float* lsumW  = (float*)(sm + 32768 + 2048 + 256);   // [8]

  const int tid  = threadIdx.x;
  const int lane = tid & 63;
  const int wv   = tid >> 6;        // wave 0..7
  const int col  = lane & 15;
  const int hi   = lane >> 4;       // 0..3
  const int b32  = blockIdx.x * 32;

  // ---- azc: m1 A-fragments for C-rows 0..15 (rt=0), register-resident ----
  // A-fragment (kk, rt=0): row = col, elems z[row][kk*32 + hi*8 .. +7].
  bf16x8 azc[8];
  {
    const float* base = z + (size_t)(b32 + col)*256 + hi*8;
    #pragma unroll
    for (int kk = 0; kk < 8; ++kk) {
      float4 a0 = *reinterpret_cast<const float4*>(base + kk*32);
      float4 a1 = *reinterpret_cast<const float4*>(base + kk*32 + 4);
      azc[kk] = pack8(a0, a1);
    }
  }

  // ---- stage z rows 16..63: fp32 -> bf16 unit-major zb3 (j=0 skipped) ----
  #pragma unroll
  for (int j = 1; j < 4; ++j) {
    int lin = j*512 + tid;              // 512..2047 units
    int row = lin >> 5;                 // 16..63
    int u   = lin & 31;                 // 0..31
    int grow = (row < 32) ? (b32 + row) : (16384 + b32 + row - 32);
    const float4* src = reinterpret_cast<const float4*>(z + (size_t)grow*256 + u*8);
    float4 v0 = src[0], v1 = src[1];
    uint32_t w0 = (uint32_t)f2bf(v0.x) | ((uint32_t)f2bf(v0.y) << 16);
    uint32_t w1 = (uint32_t)f2bf(v0.z) | ((uint32_t)f2bf(v0.w) << 16);
    uint32_t w2 = (uint32_t)f2bf(v1.x) | ((uint32_t)f2bf(v1.y) << 16);
    uint32_t w3 = (uint32_t)f2bf(v1.z) | ((uint32_t)f2bf(v1.w) << 16);
    uint32_t* p = reinterpret_cast<uint32_t*>(sm + u*1024 + row*16);
    p[0] = w0; p[1] = w1; p[2] = w2; p[3] = w3;
  }
  __syncthreads();

  f32x4 accQ[4][2] = {};      // Q accumulator: 4 row-tiles x 2 d-col-tiles
  float dn[4][4] = {};        // denominator partials per (row-tile, reg)
  float lsum = 0.0f;

  // lane-resident LDS bases (computed once)
  const unsigned char* zA = sm + (hi*1024 + col*16);            // m1 A reads
  // P store base: value (row = rt*16+hi*4+rg, k = wv*16+col) lives at
  // (k>>5)*4096 + ((k>>3)&3)*1024 + row*16 + (k&7)*2
  const int pstore_off = (wv >> 1)*4096 + ((((wv & 1) << 1) | (col >> 3)))*1024
                       + hi*64 + (col & 7)*2;

  #pragma unroll 1
  for (int kt = 0; kt < 8; ++kt) {
    const int ke0 = kt*128 + wv*16;     // this wave's emb-row base
    const int pbuf = 32768 + (kt & 1)*16384;

    // ---- region 1: mb prefetch + ciphers + m1 MFMAs ----
    const unsigned short* ebase = Eb + (size_t)(ke0 + col)*256 + hi*8;
    bf16x8 mb[8];
    #pragma unroll
    for (int kk = 0; kk < 8; ++kk)
      mb[kk] = *reinterpret_cast<const bf16x8*>(ebase + kk*32);

    float enk = enorm[ke0 + col];

    TF2 c[2][4];                       // ciphers: zero data dependencies
    #pragma unroll
    for (int rt = 0; rt < 2; ++rt) {
      #pragma unroll
      for (int rg = 0; rg < 4; ++rg) {
        int rowL = rt*16 + hi*4 + rg;                       // G0 row (0..31)
        uint32_t idx = (uint32_t)(b32 + rowL)*1024u + (uint32_t)(ke0 + col);
        c[rt][rg] = tf2x32(GKEY.a, GKEY.b, idx, idx + (1u<<24)); // (t, t+16384)
      }
    }

    f32x4 aS[4] = {};
    __builtin_amdgcn_s_setprio(1);
    #pragma unroll
    for (int kk = 0; kk < 8; ++kk) {
      aS[0] = MFMA16(azc[kk], mb[kk], aS[0]);    // rt=0 from registers
      #pragma unroll
      for (int rt = 1; rt < 4; ++rt) {
        bf16x8 af = *reinterpret_cast<const bf16x8*>(zA + kk*4096 + rt*256);
        aS[rt] = MFMA16(af, mb[kk], aS[rt]);
      }
    }
    __builtin_amdgcn_s_setprio(0);

    // ---- region 2: nb prefetch + exp/pack/store P ----
    const unsigned short* etb0 = ETb + (size_t)(wv*32 + col)*1024 + kt*128 + hi*8;
    const unsigned short* etb1 = etb0 + 16*1024;
    bf16x8 nb[8];
    #pragma unroll
    for (int kk = 0; kk < 4; ++kk) {
      nb[kk]   = *reinterpret_cast<const bf16x8*>(etb0 + kk*32);
      nb[kk+4] = *reinterpret_cast<const bf16x8*>(etb1 + kk*32);
    }

    unsigned char* sb = sm + pbuf + pstore_off;
    #pragma unroll
    for (int rt = 0; rt < 2; ++rt) {
      #pragma unroll
      for (int rg = 0; rg < 4; ++rg) {
        float p0 = __expf(fmaf(2.0f, aS[rt  ][rg], -enk)) * gumbel_w(c[rt][rg].a);
        float p1 = __expf(fmaf(2.0f, aS[rt+2][rg], -enk)) * gumbel_w(c[rt][rg].b);
        dn[rt  ][rg] += p0;
        dn[rt+2][rg] += p1;
        *(unsigned short*)(sb + rt*256 + rg*16)       = f2bf(p0);  // rows 0..31
        *(unsigned short*)(sb + rt*256 + rg*16 + 512) = f2bf(p1);  // rows 32..63
      }
    }
    __syncthreads();

    // ---- region 3: m2 MFMAs (P via base+imm, no global loads) ----
    const unsigned char* pA = sm + pbuf + (hi*1024 + col*16);
    __builtin_amdgcn_s_setprio(1);
    #pragma unroll
    for (int kk = 0; kk < 4; ++kk) {
      #pragma unroll
      for (int rt = 0; rt < 4; ++rt) {
        bf16x8 af = *reinterpret_cast<const bf16x8*>(pA + kk*4096 + rt*256);
        accQ[rt][0] = MFMA16(af, nb[kk],   accQ[rt][0]);
        accQ[rt][1] = MFMA16(af, nb[kk+4], accQ[rt][1]);
      }
    }
    __builtin_amdgcn_s_setprio(0);
    // no second barrier: next iteration writes the other P buffer
  }
  __syncthreads();   // protect reduction-scratch reuse of Pl2

  // ---- denominator: reduce over 16 lanes (this wave's cols), then 8 waves ----
  #pragma unroll
  for (int rt = 0; rt < 4; ++rt)
    #pragma unroll
    for (int rg = 0; rg < 4; ++rg) {
      float v = dn[rt][rg];
      v += __shfl_xor(v, 1);
      v += __shfl_xor(v, 2);
      v += __shfl_xor(v, 4);
      v += __shfl_xor(v, 8);
      dn[rt][rg] = v;
    }
  if (col == 0) {
    #pragma unroll
    for (int rt = 0; rt < 4; ++rt)
      #pragma unroll
      for (int rg = 0; rg < 4; ++rg)
        denomW[wv*64 + rt*16 + hi*4 + rg] = dn[rt][rg];
  }
  __syncthreads();
  if (tid < 64) {
    float s = 0.f;
    #pragma unroll
    for (int w2 = 0; w2 < 8; ++w2) s += denomW[w2*64 + tid];
    denomF[tid] = __builtin_amdgcn_rcpf(s);
  }
  __syncthreads();

  // ---- epilogue: normalize, write out0, accumulate loss partial ----
  #pragma unroll
  for (int rt = 0; rt < 4; ++rt) {
    #pragma unroll
    for (int rg = 0; rg < 4; ++rg) {
      int row = rt*16 + hi*4 + rg;
      float rd = denomF[row];
      int grow = (row < 32) ? (b32 + row) : (16384 + b32 + row - 32);
      float* orow = out + (size_t)grow*256;
      const float* zrow = z + (size_t)grow*256;
      #pragma unroll
      for (int ct = 0; ct < 2; ++ct) {
        int d = wv*32 + ct*16 + col;
        float q  = accQ[rt][ct][rg] * rd;
        float zv = zrow[d];
        float df = q - zv;
        orow[d] = zv + df;          // straight-through value == quantized
        lsum += df*df;
      }
    }
  }
  #pragma unroll
  for (int o = 32; o > 0; o >>= 1) lsum += __shfl_down(lsum, o);
  if (lane == 0) lsumW[wv] = lsum;
  __syncthreads();
  if (tid == 0) {
    float s = 0.f;
    #pragma unroll
    for (int w2 = 0; w2 < 8; ++w2) s += lsumW[w2];
    partials[blockIdx.x] = s;
  }
}

// ---------------------------------------------------------------------------
// Final: loss = 1.25 * sum(partials) / 2^23
// ---------------------------------------------------------------------------
__global__ void gq_final(const float* __restrict__ partials, float* __restrict__ out)
{
  const int t = threadIdx.x;   // 512
  float v = partials[t];
  #pragma unroll
  for (int o = 32; o > 0; o >>= 1) v += __shfl_down(v, o);
  __shared__ float ws8[8];
  if ((t & 63) == 0) ws8[t >> 6] = v;
  __syncthreads();
  if (t == 0) {
    float s = 0.f;
    #pragma unroll
    for (int i = 0; i < 8; ++i) s += ws8[i];
    out[8388608] = 1.25f * s * (1.0f / 8388608.0f);
  }
}

extern "C" void kernel_launch(void* const* d_in, const int* in_sizes, int n_in,
                              void* d_out, int out_size, void* d_ws, size_t ws_size,
                              hipStream_t stream)
{
  const float* z   = (const float*)d_in[0];   // [32,1024,256]
  const float* emb = (const float*)d_in[1];   // [1024,256]
  float* out = (float*)d_out;                 // 8388608 + 1
  char* ws = (char*)d_ws;
  unsigned short* Eb  = (unsigned short*)ws;               // 524288 B
  unsigned short* ETb = (unsigned short*)(ws + 524288);    // 524288 B
  float* enorm    = (float*)(ws + 1048576);                // 4096 B
  float* partials = (float*)(ws + 1048576 + 4096);         // 2048 B

  gq_prep<<<1024, 256, 0, stream>>>(emb, Eb, ETb, enorm);
  gq_main<<<512, 512, 0, stream>>>(z, Eb, ETb, enorm, out, partials);
  gq_final<<<1, 512, 0, stream>>>(partials, out);
}

// Round 20
// 91.331 us; speedup vs baseline: 1.3785x; 1.0129x over previous
//
#include <hip/hip_runtime.h>
#include <hip/hip_bf16.h>
#include <stdint.h>

// ---------------------------------------------------------------------------
// GumbelQuantizer: z[32768,256] fp32, emb[1024,256] fp32 ->
//   out0 = softmax((-d + gumbel)) @ emb  (straight-through == quantized)
//   out1 = 1.25 * mean((quantized - z)^2)
// s_k = 2 z.e_k - |e_k|^2 (row-constant -|z|^2 cancels). Gumbel via exact JAX
// threefry2x32; e^g = rcp(-log2 u) (global 1/ln2 cancels in softmax).
//
// R21 = R14 restored (session-best, 90.9us measured). Session conclusion:
// - Wins: (512,2) register budget fix (219->92.5); unit-major zero-VALU LDS
//   addressing + conflict fix (92.5->90.9); the fused 2-matmul design itself.
// - Eliminated: VALU-bound (R19: VALUBusy 18.5% at same perf), LDS-read-bound
//   (R20 neutral), occupancy (R15: VGPR quantum pins 16 waves/CU), barrier
//   domains (R4/R10/R11/R12/R16 worse), intra-wave reorders (R8/R9/R13 worse,
//   in-order issue), barrier drain (R18 neutral).
// - Binding constraint: per-tile serial chains (L2 load -> MFMA -> exp ->
//   store -> barrier -> MFMA) x phase-locked waves; no pipe >50%.
// ---------------------------------------------------------------------------

typedef __bf16 bf16x8 __attribute__((ext_vector_type(8)));
typedef float  f32x4  __attribute__((ext_vector_type(4)));

#define MFMA16(A,B,C) __builtin_amdgcn_mfma_f32_16x16x32_bf16((A),(B),(C),0,0,0)

struct TF2 { uint32_t a, b; };

__host__ __device__ constexpr uint32_t rotl32(uint32_t v, int r){ return (v<<r)|(v>>(32-r)); }

// Threefry-2x32, 20 rounds — exact JAX implementation.
__host__ __device__ constexpr TF2 tf2x32(uint32_t k0, uint32_t k1, uint32_t x0, uint32_t x1){
  const uint32_t k2 = k0 ^ k1 ^ 0x1BD11BDAu;
  x0 += k0; x1 += k1;
  x0 += x1; x1 = rotl32(x1,13); x1 ^= x0;
  x0 += x1; x1 = rotl32(x1,15); x1 ^= x0;
  x0 += x1; x1 = rotl32(x1,26); x1 ^= x0;
  x0 += x1; x1 = rotl32(x1, 6); x1 ^= x0;
  x0 += k1; x1 += k2 + 1u;
  x0 += x1; x1 = rotl32(x1,17); x1 ^= x0;
  x0 += x1; x1 = rotl32(x1,29); x1 ^= x0;
  x0 += x1; x1 = rotl32(x1,16); x1 ^= x0;
  x0 += x1; x1 = rotl32(x1,24); x1 ^= x0;
  x0 += k2; x1 += k0 + 2u;
  x0 += x1; x1 = rotl32(x1,13); x1 ^= x0;
  x0 += x1; x1 = rotl32(x1,15); x1 ^= x0;
  x0 += x1; x1 = rotl32(x1,26); x1 ^= x0;
  x0 += x1; x1 = rotl32(x1, 6); x1 ^= x0;
  x0 += k0; x1 += k1 + 3u;
  x0 += x1; x1 = rotl32(x1,17); x1 ^= x0;
  x0 += x1; x1 = rotl32(x1,29); x1 ^= x0;
  x0 += x1; x1 = rotl32(x1,16); x1 ^= x0;
  x0 += x1; x1 = rotl32(x1,24); x1 ^= x0;
  x0 += k1; x1 += k2 + 4u;
  x0 += x1; x1 = rotl32(x1,13); x1 ^= x0;
  x0 += x1; x1 = rotl32(x1,15); x1 ^= x0;
  x0 += x1; x1 = rotl32(x1,26); x1 ^= x0;
  x0 += x1; x1 = rotl32(x1, 6); x1 ^= x0;
  x0 += k2; x1 += k0 + 5u;
  return {x0, x1};
}

// gkey = fold_in(key(0), 1) = threefry((0,0), (0,1)) — compile-time.
constexpr TF2 GKEY = tf2x32(0u, 0u, 0u, 1u);

__device__ __forceinline__ unsigned short f2bf(float f){
  __bf16 h = (__bf16)f;
  return __builtin_bit_cast(unsigned short, h);
}

// exp(gumbel) up to a global constant: 1/(-log2 u), u = JAX uniform(tiny,1)
__device__ __forceinline__ float gumbel_w(uint32_t bits){
  float uf = __uint_as_float((bits >> 9) | 0x3f800000u) - 1.0f;
  float u  = fmaxf(uf, 1.17549435e-38f);
  return __builtin_amdgcn_rcpf(-__log2f(u));
}

// ---------------------------------------------------------------------------
// Prep: bf16 E [1024][256], bf16 E^T [256][1024], |e_k|^2 fp32 [1024]
// ---------------------------------------------------------------------------
__global__ void gq_prep(const float* __restrict__ emb, unsigned short* __restrict__ Eb,
                        unsigned short* __restrict__ ETb, float* __restrict__ enorm)
{
  const int r = blockIdx.x;       // 1024 emb rows
  const int t = threadIdx.x;      // 256 threads = one row
  float e = emb[r*256 + t];
  unsigned short h = f2bf(e);
  Eb[r*256 + t] = h;
  ETb[t*1024 + r] = h;
  float sq = e*e;
  #pragma unroll
  for (int o = 32; o > 0; o >>= 1) sq += __shfl_down(sq, o);
  __shared__ float ws4[4];
  if ((t & 63) == 0) ws4[t >> 6] = sq;
  __syncthreads();
  if (t == 0) enorm[r] = ws4[0] + ws4[1] + ws4[2] + ws4[3];
}

// ---------------------------------------------------------------------------
// Main fused kernel: 512 blocks x 512 threads (8 waves), 2 blocks/CU.
// Block b owns z rows [b*32, b*32+32) (G0) and +16384 (G1) — threefry pairs.
// LDS layout (unit-major, 16B units, zero-VALU addressing):
//   zb3  at [0, 32768):       unit(kk 0..7, hi 0..3, row 0..63) =
//                             z[row][kk*32+hi*8 .. +7] bf16
//                             byte = kk*4096 + hi*1024 + row*16
//   Pl2  at [32768, 65536):   2 buffers x 16KB; unit(kk 0..3, hi, row)
// All ds accesses: one lane-resident base reg + compile-time offset.
// Wave w owns emb-col stripe w*16 per 128-k tile (m1/gumbel) and d-cols
// [w*32,+32) of the output (m2).
// ---------------------------------------------------------------------------
__global__ __launch_bounds__(512, 2)   // empirically: 128-VGPR budget
void gq_main(
    const float* __restrict__ z, const unsigned short* __restrict__ Eb,
    const unsigned short* __restrict__ ETb, const float* __restrict__ enorm,
    float* __restrict__ out, float* __restrict__ partials)
{
  __shared__ __align__(16) unsigned char sm[32768 + 32768];
  float* denomW = (float*)(sm + 32768);                // reuse Pl2: [8][64]
  float* denomF = (float*)(sm + 32768 + 2048);         // [64]
  float* lsumW  = (float*)(sm + 32768 + 2048 + 256);   // [8]

  const int tid  = threadIdx.x;
  const int lane = tid & 63;
  const int wv   = tid >> 6;        // wave 0..7
  const int col  = lane & 15;
  const int hi   = lane >> 4;       // 0..3
  const int b32  = blockIdx.x * 32;

  // ---- stage z: fp32 -> bf16 unit-major zb3 ----
  #pragma unroll
  for (int j = 0; j < 4; ++j) {
    int lin = j*512 + tid;              // 0..2047 units
    int row = lin >> 5;                 // 0..63
    int u   = lin & 31;                 // 0..31
    int grow = (row < 32) ? (b32 + row) : (16384 + b32 + row - 32);
    const float4* src = reinterpret_cast<const float4*>(z + (size_t)grow*256 + u*8);
    float4 v0 = src[0], v1 = src[1];
    uint32_t w0 = (uint32_t)f2bf(v0.x) | ((uint32_t)f2bf(v0.y) << 16);
    uint32_t w1 = (uint32_t)f2bf(v0.z) | ((uint32_t)f2bf(v0.w) << 16);
    uint32_t w2 = (uint32_t)f2bf(v1.x) | ((uint32_t)f2bf(v1.y) << 16);
    uint32_t w3 = (uint32_t)f2bf(v1.z) | ((uint32_t)f2bf(v1.w) << 16);
    uint32_t* p = reinterpret_cast<uint32_t*>(sm + u*1024 + row*16);
    p[0] = w0; p[1] = w1; p[2] = w2; p[3] = w3;
  }
  __syncthreads();

  f32x4 accQ[4][2] = {};      // Q accumulator: 4 row-tiles x 2 d-col-tiles
  float dn[4][4] = {};        // denominator partials per (row-tile, reg)
  float lsum = 0.0f;

  // lane-resident LDS bases (computed once)
  const unsigned char* zA = sm + (hi*1024 + col*16);            // m1 A reads
  // P store base: value (row = rt*16+hi*4+rg, k = wv*16+col) lives at
  // (k>>5)*4096 + ((k>>3)&3)*1024 + row*16 + (k&7)*2
  const int pstore_off = (wv >> 1)*4096 + ((((wv & 1) << 1) | (col >> 3)))*1024
                       + hi*64 + (col & 7)*2;

  #pragma unroll 1
  for (int kt = 0; kt < 8; ++kt) {
    const int ke0 = kt*128 + wv*16;     // this wave's emb-row base
    const int pbuf = 32768 + (kt & 1)*16384;

    // ---- region 1: mb prefetch + ciphers + m1 MFMAs ----
    const unsigned short* ebase = Eb + (size_t)(ke0 + col)*256 + hi*8;
    bf16x8 mb[8];
    #pragma unroll
    for (int kk = 0; kk < 8; ++kk)
      mb[kk] = *reinterpret_cast<const bf16x8*>(ebase + kk*32);

    float enk = enorm[ke0 + col];

    TF2 c[2][4];                       // ciphers: zero data dependencies
    #pragma unroll
    for (int rt = 0; rt < 2; ++rt) {
      #pragma unroll
      for (int rg = 0; rg < 4; ++rg) {
        int rowL = rt*16 + hi*4 + rg;                       // G0 row (0..31)
        uint32_t idx = (uint32_t)(b32 + rowL)*1024u + (uint32_t)(ke0 + col);
        c[rt][rg] = tf2x32(GKEY.a, GKEY.b, idx, idx + (1u<<24)); // (t, t+16384)
      }
    }

    f32x4 aS[4] = {};
    __builtin_amdgcn_s_setprio(1);
    #pragma unroll
    for (int kk = 0; kk < 8; ++kk) {
      #pragma unroll
      for (int rt = 0; rt < 4; ++rt) {
        bf16x8 af = *reinterpret_cast<const bf16x8*>(zA + kk*4096 + rt*256);
        aS[rt] = MFMA16(af, mb[kk], aS[rt]);
      }
    }
    __builtin_amdgcn_s_setprio(0);

    // ---- region 2: nb prefetch + exp/pack/store P ----
    const unsigned short* etb0 = ETb + (size_t)(wv*32 + col)*1024 + kt*128 + hi*8;
    const unsigned short* etb1 = etb0 + 16*1024;
    bf16x8 nb[8];
    #pragma unroll
    for (int kk = 0; kk < 4; ++kk) {
      nb[kk]   = *reinterpret_cast<const bf16x8*>(etb0 + kk*32);
      nb[kk+4] = *reinterpret_cast<const bf16x8*>(etb1 + kk*32);
    }

    unsigned char* sb = sm + pbuf + pstore_off;
    #pragma unroll
    for (int rt = 0; rt < 2; ++rt) {
      #pragma unroll
      for (int rg = 0; rg < 4; ++rg) {
        float p0 = __expf(fmaf(2.0f, aS[rt  ][rg], -enk)) * gumbel_w(c[rt][rg].a);
        float p1 = __expf(fmaf(2.0f, aS[rt+2][rg], -enk)) * gumbel_w(c[rt][rg].b);
        dn[rt  ][rg] += p0;
        dn[rt+2][rg] += p1;
        *(unsigned short*)(sb + rt*256 + rg*16)       = f2bf(p0);  // rows 0..31
        *(unsigned short*)(sb + rt*256 + rg*16 + 512) = f2bf(p1);  // rows 32..63
      }
    }
    __syncthreads();

    // ---- region 3: m2 MFMAs (P via base+imm, no global loads) ----
    const unsigned char* pA = sm + pbuf + (hi*1024 + col*16);
    __builtin_amdgcn_s_setprio(1);
    #pragma unroll
    for (int kk = 0; kk < 4; ++kk) {
      #pragma unroll
      for (int rt = 0; rt < 4; ++rt) {
        bf16x8 af = *reinterpret_cast<const bf16x8*>(pA + kk*4096 + rt*256);
        accQ[rt][0] = MFMA16(af, nb[kk],   accQ[rt][0]);
        accQ[rt][1] = MFMA16(af, nb[kk+4], accQ[rt][1]);
      }
    }
    __builtin_amdgcn_s_setprio(0);
    // no second barrier: next iteration writes the other P buffer
  }
  __syncthreads();   // protect reduction-scratch reuse of Pl2

  // ---- denominator: reduce over 16 lanes (this wave's cols), then 8 waves ----
  #pragma unroll
  for (int rt = 0; rt < 4; ++rt)
    #pragma unroll
    for (int rg = 0; rg < 4; ++rg) {
      float v = dn[rt][rg];
      v += __shfl_xor(v, 1);
      v += __shfl_xor(v, 2);
      v += __shfl_xor(v, 4);
      v += __shfl_xor(v, 8);
      dn[rt][rg] = v;
    }
  if (col == 0) {
    #pragma unroll
    for (int rt = 0; rt < 4; ++rt)
      #pragma unroll
      for (int rg = 0; rg < 4; ++rg)
        denomW[wv*64 + rt*16 + hi*4 + rg] = dn[rt][rg];
  }
  __syncthreads();
  if (tid < 64) {
    float s = 0.f;
    #pragma unroll
    for (int w2 = 0; w2 < 8; ++w2) s += denomW[w2*64 + tid];
    denomF[tid] = __builtin_amdgcn_rcpf(s);
  }
  __syncthreads();

  // ---- epilogue: normalize, write out0, accumulate loss partial ----
  #pragma unroll
  for (int rt = 0; rt < 4; ++rt) {
    #pragma unroll
    for (int rg = 0; rg < 4; ++rg) {
      int row = rt*16 + hi*4 + rg;
      float rd = denomF[row];
      int grow = (row < 32) ? (b32 + row) : (16384 + b32 + row - 32);
      float* orow = out + (size_t)grow*256;
      const float* zrow = z + (size_t)grow*256;
      #pragma unroll
      for (int ct = 0; ct < 2; ++ct) {
        int d = wv*32 + ct*16 + col;
        float q  = accQ[rt][ct][rg] * rd;
        float zv = zrow[d];
        float df = q - zv;
        orow[d] = zv + df;          // straight-through value == quantized
        lsum += df*df;
      }
    }
  }
  #pragma unroll
  for (int o = 32; o > 0; o >>= 1) lsum += __shfl_down(lsum, o);
  if (lane == 0) lsumW[wv] = lsum;
  __syncthreads();
  if (tid == 0) {
    float s = 0.f;
    #pragma unroll
    for (int w2 = 0; w2 < 8; ++w2) s += lsumW[w2];
    partials[blockIdx.x] = s;
  }
}

// ---------------------------------------------------------------------------
// Final: loss = 1.25 * sum(partials) / 2^23
// ---------------------------------------------------------------------------
__global__ void gq_final(const float* __restrict__ partials, float* __restrict__ out)
{
  const int t = threadIdx.x;   // 512
  float v = partials[t];
  #pragma unroll
  for (int o = 32; o > 0; o >>= 1) v += __shfl_down(v, o);
  __shared__ float ws8[8];
  if ((t & 63) == 0) ws8[t >> 6] = v;
  __syncthreads();
  if (t == 0) {
    float s = 0.f;
    #pragma unroll
    for (int i = 0; i < 8; ++i) s += ws8[i];
    out[8388608] = 1.25f * s * (1.0f / 8388608.0f);
  }
}

extern "C" void kernel_launch(void* const* d_in, const int* in_sizes, int n_in,
                              void* d_out, int out_size, void* d_ws, size_t ws_size,
                              hipStream_t stream)
{
  const float* z   = (const float*)d_in[0];   // [32,1024,256]
  const float* emb = (const float*)d_in[1];   // [1024,256]
  float* out = (float*)d_out;                 // 8388608 + 1
  char* ws = (char*)d_ws;
  unsigned short* Eb  = (unsigned short*)ws;               // 524288 B
  unsigned short* ETb = (unsigned short*)(ws + 524288);    // 524288 B
  float* enorm    = (float*)(ws + 1048576);                // 4096 B
  float* partials = (float*)(ws + 1048576 + 4096);         // 2048 B

  gq_prep<<<1024, 256, 0, stream>>>(emb, Eb, ETb, enorm);
  gq_main<<<512, 512, 0, stream>>>(z, Eb, ETb, enorm, out, partials);
  gq_final<<<1, 512, 0, stream>>>(partials, out);
}